// Round 14
// baseline (194.036 us; speedup 1.0000x reference)
//
#include <hip/hip_runtime.h>
#include <hip/hip_fp16.h>
#include <hip/hip_cooperative_groups.h>

namespace cg = cooperative_groups;

#define LATENT 128
#define DQK    32
#define BB     4
#define NN     16384
#define KK     64
#define TOTAL_EDGES (BB * NN * KK)   // 4,194,304
#define TOTAL_NODES (BB * NN)        // 65,536
#define PADF   132                   // f32 LDS row stride (floats)
#define PADH   132                   // f16 LDS row stride (halves)
#define EPT    4                     // edges per thread per edge-iteration
#define COOP_BLOCKS 256              // 1 block/CU under HIP's 64KB shared-mem belief

// ---------------------------------------------------------------------------
__device__ __forceinline__ int dot4i8(int a, int b, int c) {
#if __has_builtin(__builtin_amdgcn_sdot4)
    return __builtin_amdgcn_sdot4(a, b, c, false);
#else
    c += ((a << 24) >> 24) * ((b << 24) >> 24);
    c += ((a << 16) >> 24) * ((b << 16) >> 24);
    c += ((a <<  8) >> 24) * ((b <<  8) >> 24);
    c += (a >> 24) * (b >> 24);
    return c;
#endif
}

// ===========================================================================
// Cooperative fused kernel: LDS union = 65536 B exactly.
//   proj role uses 50.9 KB (sf f32 33.8K | swh f16 16.9K | sb 256B)
//   edge role uses 65536 B (ssk 32K | ssq 32K)
// 256 blocks x 512 threads -> 1 block/CU; edge floor is occupancy-invariant
// (r8: 33% -> 50us, r9: 66% -> 54us), so 8 waves/CU should hold ~50us.
// ===========================================================================
__global__ __launch_bounds__(512, 2) void fused_kernel(
    const float* __restrict__ features,  // [B*N, 128]
    const float* __restrict__ Wk,        // [32, 128]
    const float* __restrict__ bk,        // [32]
    const float* __restrict__ Wq,        // [32, 128]
    const float* __restrict__ bq,        // [32]
    const int* __restrict__ xidx,        // indices row 1, [B*N*K]
    const int* __restrict__ yidx,        // indices row 2
    signed char* __restrict__ ks8,       // [B*N, 32] i8
    signed char* __restrict__ qs8,
    __half* __restrict__ sk,             // [B*N] f16 row scales
    __half* __restrict__ sq,
    float* __restrict__ out)             // [B*N*K]
{
    __shared__ __align__(16) unsigned char smem[65536];

    const int t = threadIdx.x;
    const int bid = blockIdx.x;

    // ======================= Phase 1: projection =======================
    {
        float*  sf  = (float*)smem;                     // 64 x PADF f32
        __half* swh = (__half*)(sf + 64 * PADF);        // 64 x PADH f16
        float*  sb  = (float*)(swh + 64 * PADH);        // 64 f32

        // Stage W (f16) + biases once per block
        #pragma unroll
        for (int j = 0; j < 4; ++j) {
            int idx = t + j * 512;
            int r = idx >> 5;
            int c = idx & 31;
            const float4* src = (r < 32) ? (const float4*)Wk : (const float4*)Wq;
            float4 v = src[(size_t)(r & 31) * 32 + c];
            *(__half2*)&swh[r * PADH + c * 4]     = __floats2half2_rn(v.x, v.y);
            *(__half2*)&swh[r * PADH + c * 4 + 2] = __floats2half2_rn(v.z, v.w);
        }
        if (t < 64) sb[t] = (t < 32) ? bk[t] : bq[t - 32];

        const int tx = t & 15;               // dims tx + 16u
        const int ty = t >> 4;               // node groups: nodes ty*2 + i

        // 256 nodes per block = 4 tiles of 64
        for (int tile = 0; tile < 4; ++tile) {
            const int node0 = bid * 256 + tile * 64;

            __syncthreads();   // protect sf from previous tile's readers
            #pragma unroll
            for (int j = 0; j < 4; ++j) {
                int idx = t + j * 512;
                int r = idx >> 5;
                int c = idx & 31;
                float4 v = ((const float4*)(features + (size_t)(node0 + r) * LATENT))[c];
                *(float4*)&sf[r * PADF + c * 4] = v;
            }
            __syncthreads();

            float acc[2][4];
            #pragma unroll
            for (int i = 0; i < 2; ++i)
                #pragma unroll
                for (int u = 0; u < 4; ++u) acc[i][u] = 0.f;

            #pragma unroll 4
            for (int kk = 0; kk < 32; ++kk) {
                float4 a[2], b[4];
                #pragma unroll
                for (int i = 0; i < 2; ++i)
                    a[i] = *(const float4*)&sf[(ty * 2 + i) * PADF + kk * 4];
                #pragma unroll
                for (int u = 0; u < 4; ++u) {
                    const int row = tx + 16 * u;
                    float2 f01 = __half22float2(*(const __half2*)&swh[row * PADH + kk * 4]);
                    float2 f23 = __half22float2(*(const __half2*)&swh[row * PADH + kk * 4 + 2]);
                    b[u] = make_float4(f01.x, f01.y, f23.x, f23.y);
                }
                #pragma unroll
                for (int i = 0; i < 2; ++i)
                    #pragma unroll
                    for (int u = 0; u < 4; ++u)
                        acc[i][u] += a[i].x * b[u].x + a[i].y * b[u].y
                                   + a[i].z * b[u].z + a[i].w * b[u].w;
            }

            // quantizing epilogue
            float vk0[2], vk1[2], vq0[2], vq1[2], mk[2], mq[2];
            #pragma unroll
            for (int i = 0; i < 2; ++i) {
                vk0[i] = acc[i][0] + sb[tx];
                vk1[i] = acc[i][1] + sb[tx + 16];
                vq0[i] = acc[i][2] + sb[tx + 32];
                vq1[i] = acc[i][3] + sb[tx + 48];
                mk[i] = fmaxf(fabsf(vk0[i]), fabsf(vk1[i]));
                mq[i] = fmaxf(fabsf(vq0[i]), fabsf(vq1[i]));
            }
            #pragma unroll
            for (int mask = 1; mask < 16; mask <<= 1) {
                #pragma unroll
                for (int i = 0; i < 2; ++i) {
                    mk[i] = fmaxf(mk[i], __shfl_xor(mk[i], mask));
                    mq[i] = fmaxf(mq[i], __shfl_xor(mq[i], mask));
                }
            }
            #pragma unroll
            for (int i = 0; i < 2; ++i) {
                const int node = node0 + ty * 2 + i;
                const float invk = (mk[i] > 0.f) ? 127.f / mk[i] : 0.f;
                const float invq = (mq[i] > 0.f) ? 127.f / mq[i] : 0.f;
                signed char* kr = ks8 + (size_t)node * 32;
                signed char* qr = qs8 + (size_t)node * 32;
                kr[tx]      = (signed char)__float2int_rn(vk0[i] * invk);
                kr[tx + 16] = (signed char)__float2int_rn(vk1[i] * invk);
                qr[tx]      = (signed char)__float2int_rn(vq0[i] * invq);
                qr[tx + 16] = (signed char)__float2int_rn(vq1[i] * invq);
                if (tx == 0) {
                    sk[node] = __float2half(mk[i] * (1.f / 127.f));
                    sq[node] = __float2half(mq[i] * (1.f / 127.f));
                }
            }
        }
    }

    __threadfence();
    cg::this_grid().sync();

    // ======================= Phase 2: edge dots =======================
    {
        __half* ssk = (__half*)smem;          // NN f16 = 32 KB
        __half* ssq = ssk + NN;               // 32 KB

        const int b = bid >> 6;               // 64 blocks per batch
        const int lbid = bid & 63;            // block within batch

        __syncthreads();                      // all lanes done with proj LDS
        const uint4* gk = (const uint4*)(sk + (size_t)b * NN);
        const uint4* gq = (const uint4*)(sq + (size_t)b * NN);
        uint4* lk = (uint4*)ssk;
        uint4* lq = (uint4*)ssq;
        #pragma unroll
        for (int j = 0; j < 4; ++j) {
            lk[t + j * 512] = gk[t + j * 512];
            lq[t + j * 512] = gq[t + j * 512];
        }
        __syncthreads();

        const int gbase = b << 20;                 // batch edge offset
        const size_t nodebase = (size_t)b << 14;   // b * NN
        const uint4* k4 = (const uint4*)ks8;
        const uint4* q4 = (const uint4*)qs8;

        // 16384 edges per block = 8 iterations of the r8 block-body
        for (int it = 0; it < 8; ++it) {
            const int base_e = lbid * 16384 + it * 2048;   // within batch

            int xs[EPT], ys[EPT];
            #pragma unroll
            for (int m = 0; m < EPT; ++m) {
                const int e = base_e + m * 512 + t;
                xs[m] = xidx[gbase + e];
                ys[m] = yidx[gbase + e];
            }
            __builtin_amdgcn_sched_barrier(0);

            uint4 kv0[EPT], kv1[EPT], qv0[EPT], qv1[EPT];
            #pragma unroll
            for (int m = 0; m < EPT; ++m) {
                const size_t xo = (nodebase + (size_t)xs[m]) << 1;  // uint4 units
                const size_t yo = (nodebase + (size_t)ys[m]) << 1;
                kv0[m] = k4[xo];
                kv1[m] = k4[xo + 1];
                qv0[m] = q4[yo];
                qv1[m] = q4[yo + 1];
            }
            __builtin_amdgcn_sched_barrier(0);

            #pragma unroll
            for (int m = 0; m < EPT; ++m) {
                int d = 0;
                d = dot4i8((int)kv0[m].x, (int)qv0[m].x, d);
                d = dot4i8((int)kv0[m].y, (int)qv0[m].y, d);
                d = dot4i8((int)kv0[m].z, (int)qv0[m].z, d);
                d = dot4i8((int)kv0[m].w, (int)qv0[m].w, d);
                d = dot4i8((int)kv1[m].x, (int)qv1[m].x, d);
                d = dot4i8((int)kv1[m].y, (int)qv1[m].y, d);
                d = dot4i8((int)kv1[m].z, (int)qv1[m].z, d);
                d = dot4i8((int)kv1[m].w, (int)qv1[m].w, d);
                const float skx = __half2float(ssk[xs[m]]);
                const float sqy = __half2float(ssq[ys[m]]);
                const int e = base_e + m * 512 + t;
                out[gbase + e] = (float)d * skx * sqy * 0.17677669529663687f;
            }
        }
    }
}

// ===========================================================================
// Fallback path: exact r8 two-kernel pipeline (proven 74us) used only if the
// cooperative launch is rejected. Deterministic: same output either way.
// ===========================================================================
__global__ __launch_bounds__(256, 2) void proj_kernel(
    const float* __restrict__ features, const float* __restrict__ Wk,
    const float* __restrict__ bk, const float* __restrict__ Wq,
    const float* __restrict__ bq, signed char* __restrict__ ks8,
    signed char* __restrict__ qs8, __half* __restrict__ sk,
    __half* __restrict__ sq)
{
    __shared__ float sf[64 * PADF];
    __shared__ float sw[64 * PADF];
    __shared__ float sb[64];

    const int t = threadIdx.x;
    const int node0 = blockIdx.x * 64;

    #pragma unroll
    for (int j = 0; j < 8; ++j) {
        int idx = t + j * 256;
        int r = idx >> 5;
        int c = idx & 31;
        const float4* src = (r < 32) ? (const float4*)Wk : (const float4*)Wq;
        float4 v = src[(size_t)(r & 31) * 32 + c];
        *(float4*)&sw[r * PADF + c * 4] = v;
    }
    if (t < 64) sb[t] = (t < 32) ? bk[t] : bq[t - 32];

    #pragma unroll
    for (int j = 0; j < 8; ++j) {
        int idx = t + j * 256;
        int r = idx >> 5;
        int c = idx & 31;
        float4 v = ((const float4*)(features + (size_t)(node0 + r) * LATENT))[c];
        *(float4*)&sf[r * PADF + c * 4] = v;
    }
    __syncthreads();

    const int tx = t & 15;
    const int ty = t >> 4;

    float acc[4][4];
    #pragma unroll
    for (int i = 0; i < 4; ++i)
        #pragma unroll
        for (int u = 0; u < 4; ++u) acc[i][u] = 0.f;

    #pragma unroll 4
    for (int kk = 0; kk < 32; ++kk) {
        float4 a[4], b[4];
        #pragma unroll
        for (int i = 0; i < 4; ++i)
            a[i] = *(const float4*)&sf[(ty * 4 + i) * PADF + kk * 4];
        #pragma unroll
        for (int u = 0; u < 4; ++u)
            b[u] = *(const float4*)&sw[(tx + 16 * u) * PADF + kk * 4];
        #pragma unroll
        for (int i = 0; i < 4; ++i)
            #pragma unroll
            for (int u = 0; u < 4; ++u)
                acc[i][u] += a[i].x * b[u].x + a[i].y * b[u].y
                           + a[i].z * b[u].z + a[i].w * b[u].w;
    }

    float vk0[4], vk1[4], vq0[4], vq1[4], mk[4], mq[4];
    #pragma unroll
    for (int i = 0; i < 4; ++i) {
        vk0[i] = acc[i][0] + sb[tx];
        vk1[i] = acc[i][1] + sb[tx + 16];
        vq0[i] = acc[i][2] + sb[tx + 32];
        vq1[i] = acc[i][3] + sb[tx + 48];
        mk[i] = fmaxf(fabsf(vk0[i]), fabsf(vk1[i]));
        mq[i] = fmaxf(fabsf(vq0[i]), fabsf(vq1[i]));
    }
    #pragma unroll
    for (int mask = 1; mask < 16; mask <<= 1) {
        #pragma unroll
        for (int i = 0; i < 4; ++i) {
            mk[i] = fmaxf(mk[i], __shfl_xor(mk[i], mask));
            mq[i] = fmaxf(mq[i], __shfl_xor(mq[i], mask));
        }
    }
    #pragma unroll
    for (int i = 0; i < 4; ++i) {
        const int node = node0 + ty * 4 + i;
        const float invk = (mk[i] > 0.f) ? 127.f / mk[i] : 0.f;
        const float invq = (mq[i] > 0.f) ? 127.f / mq[i] : 0.f;
        signed char* kr = ks8 + (size_t)node * 32;
        signed char* qr = qs8 + (size_t)node * 32;
        kr[tx]      = (signed char)__float2int_rn(vk0[i] * invk);
        kr[tx + 16] = (signed char)__float2int_rn(vk1[i] * invk);
        qr[tx]      = (signed char)__float2int_rn(vq0[i] * invq);
        qr[tx + 16] = (signed char)__float2int_rn(vq1[i] * invq);
        if (tx == 0) {
            sk[node] = __float2half(mk[i] * (1.f / 127.f));
            sq[node] = __float2half(mq[i] * (1.f / 127.f));
        }
    }
}

__global__ __launch_bounds__(512, 2) void edge_kernel(
    const int* __restrict__ xidx, const int* __restrict__ yidx,
    const signed char* __restrict__ ks8, const signed char* __restrict__ qs8,
    const __half* __restrict__ sk, const __half* __restrict__ sq,
    float* __restrict__ out)
{
    __shared__ __half ssk[NN];
    __shared__ __half ssq[NN];

    const int t = threadIdx.x;
    const int b = blockIdx.x >> 9;

    const uint4* gk = (const uint4*)(sk + (size_t)b * NN);
    const uint4* gq = (const uint4*)(sq + (size_t)b * NN);
    uint4* lk = (uint4*)ssk;
    uint4* lq = (uint4*)ssq;
    #pragma unroll
    for (int j = 0; j < 4; ++j) {
        lk[t + j * 512] = gk[t + j * 512];
        lq[t + j * 512] = gq[t + j * 512];
    }
    __syncthreads();

    const int base_e = (blockIdx.x & 511) * (512 * EPT);
    const int gbase  = b << 20;
    const size_t nodebase = (size_t)b << 14;

    int xs[EPT], ys[EPT];
    #pragma unroll
    for (int m = 0; m < EPT; ++m) {
        const int e = base_e + m * 512 + t;
        xs[m] = xidx[gbase + e];
        ys[m] = yidx[gbase + e];
    }
    __builtin_amdgcn_sched_barrier(0);

    uint4 kv0[EPT], kv1[EPT], qv0[EPT], qv1[EPT];
    const uint4* k4 = (const uint4*)ks8;
    const uint4* q4 = (const uint4*)qs8;
    #pragma unroll
    for (int m = 0; m < EPT; ++m) {
        const size_t xo = (nodebase + (size_t)xs[m]) << 1;
        const size_t yo = (nodebase + (size_t)ys[m]) << 1;
        kv0[m] = k4[xo];
        kv1[m] = k4[xo + 1];
        qv0[m] = q4[yo];
        qv1[m] = q4[yo + 1];
    }
    __builtin_amdgcn_sched_barrier(0);

    #pragma unroll
    for (int m = 0; m < EPT; ++m) {
        int d = 0;
        d = dot4i8((int)kv0[m].x, (int)qv0[m].x, d);
        d = dot4i8((int)kv0[m].y, (int)qv0[m].y, d);
        d = dot4i8((int)kv0[m].z, (int)qv0[m].z, d);
        d = dot4i8((int)kv0[m].w, (int)qv0[m].w, d);
        d = dot4i8((int)kv1[m].x, (int)qv1[m].x, d);
        d = dot4i8((int)kv1[m].y, (int)qv1[m].y, d);
        d = dot4i8((int)kv1[m].z, (int)qv1[m].z, d);
        d = dot4i8((int)kv1[m].w, (int)qv1[m].w, d);
        const float skx = __half2float(ssk[xs[m]]);
        const float sqy = __half2float(ssq[ys[m]]);
        const int e = base_e + m * 512 + t;
        out[gbase + e] = (float)d * skx * sqy * 0.17677669529663687f;
    }
}

// ---------------------------------------------------------------------------
extern "C" void kernel_launch(void* const* d_in, const int* in_sizes, int n_in,
                              void* d_out, int out_size, void* d_ws, size_t ws_size,
                              hipStream_t stream) {
    // Input order: indices, img, features, Wk, bk, Wq, bq
    const int*   indices  = (const int*)d_in[0];
    const float* features = (const float*)d_in[2];
    const float* Wk       = (const float*)d_in[3];
    const float* bk       = (const float*)d_in[4];
    const float* Wq       = (const float*)d_in[5];
    const float* bq       = (const float*)d_in[6];
    float* out = (float*)d_out;

    // ws layout: ks8 (2MB) | qs8 (2MB) | sk (128KB f16) | sq (128KB f16)
    signed char* ks8 = (signed char*)d_ws;
    signed char* qs8 = ks8 + (size_t)TOTAL_NODES * 32;
    __half* sk = (__half*)(qs8 + (size_t)TOTAL_NODES * 32);
    __half* sq = sk + TOTAL_NODES;

    const int* xidx = indices + (size_t)1 * TOTAL_EDGES;  // row 1 -> keys
    const int* yidx = indices + (size_t)2 * TOTAL_EDGES;  // row 2 -> queries

    void* args[] = {
        (void*)&features, (void*)&Wk, (void*)&bk, (void*)&Wq, (void*)&bq,
        (void*)&xidx, (void*)&yidx, (void*)&ks8, (void*)&qs8,
        (void*)&sk, (void*)&sq, (void*)&out
    };
    hipError_t err = hipLaunchCooperativeKernel((const void*)fused_kernel,
                                                dim3(COOP_BLOCKS), dim3(512),
                                                args, 0, stream);
    if (err != hipSuccess) {
        // Fallback: proven r8 two-kernel pipeline.
        proj_kernel<<<TOTAL_NODES / 64, 256, 0, stream>>>(
            features, Wk, bk, Wq, bq, ks8, qs8, sk, sq);
        edge_kernel<<<BB * 512, 512, 0, stream>>>(xidx, yidx, ks8, qs8, sk, sq, out);
    }
}

// Round 15
// 77.439 us; speedup vs baseline: 2.5057x; 2.5057x over previous
//
#include <hip/hip_runtime.h>
#include <hip/hip_fp16.h>

#define LATENT 128
#define DQK    32
#define BB     4
#define NN     16384
#define KK     64
#define TOTAL_EDGES (BB * NN * KK)   // 4,194,304
#define TOTAL_NODES (BB * NN)        // 65,536
#define PADF   132                   // f32 LDS row stride (floats)
#define EPT    4                     // edges per thread (edge kernel)

// ---------------------------------------------------------------------------
// i8 dot helper
// ---------------------------------------------------------------------------
__device__ __forceinline__ int dot4i8(int a, int b, int c) {
#if __has_builtin(__builtin_amdgcn_sdot4)
    return __builtin_amdgcn_sdot4(a, b, c, false);
#else
    c += ((a << 24) >> 24) * ((b << 24) >> 24);
    c += ((a << 16) >> 24) * ((b << 16) >> 24);
    c += ((a <<  8) >> 24) * ((b <<  8) >> 24);
    c += (a >> 24) * (b >> 24);
    return c;
#endif
}

// 16B gather with sc0 (glc): bypass L1 allocation, allocate in L2.
// NOTE: no waitcnt here — caller must issue s_waitcnt vmcnt(0) + sched_barrier
// before consuming results (volatile asm preserves program order of the loads
// relative to the waitcnt asm).
__device__ __forceinline__ void load16_sc0(const uint4* p, uint4& dst) {
    asm volatile("global_load_dwordx4 %0, %1, off sc0"
                 : "=&v"(dst) : "v"(p));
}

// ---------------------------------------------------------------------------
// Kernel 1: proj + int8 row quantization (r8 version, unchanged).
// ---------------------------------------------------------------------------
__global__ __launch_bounds__(256, 2) void proj_kernel(
    const float* __restrict__ features,  // [B*N, 128]
    const float* __restrict__ Wk,        // [32, 128]
    const float* __restrict__ bk,        // [32]
    const float* __restrict__ Wq,        // [32, 128]
    const float* __restrict__ bq,        // [32]
    signed char* __restrict__ ks8,       // [B*N, 32] i8
    signed char* __restrict__ qs8,       // [B*N, 32] i8
    __half* __restrict__ sk,             // [B*N] f16 row scales
    __half* __restrict__ sq)
{
    __shared__ float sf[64 * PADF];
    __shared__ float sw[64 * PADF];      // rows 0..31 = Wk, 32..63 = Wq
    __shared__ float sb[64];

    const int t = threadIdx.x;
    const int node0 = blockIdx.x * 64;

    #pragma unroll
    for (int j = 0; j < 8; ++j) {
        int idx = t + j * 256;
        int r = idx >> 5;
        int c = idx & 31;
        const float4* src = (r < 32) ? (const float4*)Wk : (const float4*)Wq;
        float4 v = src[(size_t)(r & 31) * 32 + c];
        *(float4*)&sw[r * PADF + c * 4] = v;
    }
    if (t < 64) sb[t] = (t < 32) ? bk[t] : bq[t - 32];

    #pragma unroll
    for (int j = 0; j < 8; ++j) {
        int idx = t + j * 256;
        int r = idx >> 5;
        int c = idx & 31;
        float4 v = ((const float4*)(features + (size_t)(node0 + r) * LATENT))[c];
        *(float4*)&sf[r * PADF + c * 4] = v;
    }
    __syncthreads();

    const int tx = t & 15;               // dims tx + 16u
    const int ty = t >> 4;               // nodes ty*4 + i

    float acc[4][4];
    #pragma unroll
    for (int i = 0; i < 4; ++i)
        #pragma unroll
        for (int u = 0; u < 4; ++u) acc[i][u] = 0.f;

    #pragma unroll 4
    for (int kk = 0; kk < 32; ++kk) {
        float4 a[4], b[4];
        #pragma unroll
        for (int i = 0; i < 4; ++i)
            a[i] = *(const float4*)&sf[(ty * 4 + i) * PADF + kk * 4];
        #pragma unroll
        for (int u = 0; u < 4; ++u)
            b[u] = *(const float4*)&sw[(tx + 16 * u) * PADF + kk * 4];
        #pragma unroll
        for (int i = 0; i < 4; ++i)
            #pragma unroll
            for (int u = 0; u < 4; ++u)
                acc[i][u] += a[i].x * b[u].x + a[i].y * b[u].y
                           + a[i].z * b[u].z + a[i].w * b[u].w;
    }

    // ---- quantizing epilogue ----
    float vk0[4], vk1[4], vq0[4], vq1[4], mk[4], mq[4];
    #pragma unroll
    for (int i = 0; i < 4; ++i) {
        vk0[i] = acc[i][0] + sb[tx];
        vk1[i] = acc[i][1] + sb[tx + 16];
        vq0[i] = acc[i][2] + sb[tx + 32];
        vq1[i] = acc[i][3] + sb[tx + 48];
        mk[i] = fmaxf(fabsf(vk0[i]), fabsf(vk1[i]));
        mq[i] = fmaxf(fabsf(vq0[i]), fabsf(vq1[i]));
    }
    #pragma unroll
    for (int mask = 1; mask < 16; mask <<= 1) {
        #pragma unroll
        for (int i = 0; i < 4; ++i) {
            mk[i] = fmaxf(mk[i], __shfl_xor(mk[i], mask));
            mq[i] = fmaxf(mq[i], __shfl_xor(mq[i], mask));
        }
    }
    #pragma unroll
    for (int i = 0; i < 4; ++i) {
        const int node = node0 + ty * 4 + i;
        const float invk = (mk[i] > 0.f) ? 127.f / mk[i] : 0.f;
        const float invq = (mq[i] > 0.f) ? 127.f / mq[i] : 0.f;
        signed char* kr = ks8 + (size_t)node * 32;
        signed char* qr = qs8 + (size_t)node * 32;
        kr[tx]      = (signed char)__float2int_rn(vk0[i] * invk);
        kr[tx + 16] = (signed char)__float2int_rn(vk1[i] * invk);
        qr[tx]      = (signed char)__float2int_rn(vq0[i] * invq);
        qr[tx + 16] = (signed char)__float2int_rn(vq1[i] * invq);
        if (tx == 0) {
            sk[node] = __float2half(mk[i] * (1.f / 127.f));
            sq[node] = __float2half(mq[i] * (1.f / 127.f));
        }
    }
}

// ---------------------------------------------------------------------------
// Kernel 2: i8 edge dots — r8 config, gathers via sc0 (L1-bypass, L2-allocate).
// Single-variable test: if edge time = L1 line-fill port (2 lines x ~4cy/edge),
// sc0 should cut it to the L2 request-service floor (~4 req/edge ~ 27-35us).
// ---------------------------------------------------------------------------
__global__ __launch_bounds__(512, 2) void edge_kernel(
    const int* __restrict__ xidx,        // indices row 1, [B*N*K]
    const int* __restrict__ yidx,        // indices row 2
    const signed char* __restrict__ ks8, // [B*N, 32] i8
    const signed char* __restrict__ qs8,
    const __half* __restrict__ sk,       // [B*N] f16
    const __half* __restrict__ sq,
    float* __restrict__ out)             // [B*N*K]
{
    __shared__ __half ssk[NN];           // 32 KB
    __shared__ __half ssq[NN];           // 32 KB

    const int t = threadIdx.x;
    const int b = blockIdx.x >> 9;       // 512 blocks per batch

    // Stage scale tables (coalesced uint4: 2048 per table, 4/thread each)
    const uint4* gk = (const uint4*)(sk + (size_t)b * NN);
    const uint4* gq = (const uint4*)(sq + (size_t)b * NN);
    uint4* lk = (uint4*)ssk;
    uint4* lq = (uint4*)ssq;
    #pragma unroll
    for (int j = 0; j < 4; ++j) {
        lk[t + j * 512] = gk[t + j * 512];
        lq[t + j * 512] = gq[t + j * 512];
    }
    __syncthreads();

    const int base_e = (blockIdx.x & 511) * (512 * EPT);  // within batch
    const int gbase  = b << 20;                            // batch edge offset
    const size_t nodebase = (size_t)b << 14;               // b * NN

    // Phase 1: coalesced index loads
    int xs[EPT], ys[EPT];
    #pragma unroll
    for (int m = 0; m < EPT; ++m) {
        const int e = base_e + m * 512 + t;
        xs[m] = xidx[gbase + e];
        ys[m] = yidx[gbase + e];
    }
    __builtin_amdgcn_sched_barrier(0);

    // Phase 2: all divergent gathers in flight via sc0 (L1 bypass)
    uint4 kv0[EPT], kv1[EPT], qv0[EPT], qv1[EPT];
    const uint4* k4 = (const uint4*)ks8;
    const uint4* q4 = (const uint4*)qs8;
    #pragma unroll
    for (int m = 0; m < EPT; ++m) {
        const size_t xo = (nodebase + (size_t)xs[m]) << 1;  // uint4 units
        const size_t yo = (nodebase + (size_t)ys[m]) << 1;
        load16_sc0(k4 + xo,     kv0[m]);
        load16_sc0(k4 + xo + 1, kv1[m]);
        load16_sc0(q4 + yo,     qv0[m]);
        load16_sc0(q4 + yo + 1, qv1[m]);
    }
    asm volatile("s_waitcnt vmcnt(0)" ::: "memory");
    __builtin_amdgcn_sched_barrier(0);   // rule #18: fence VALU hoisting

    // Phase 3: lane-local i8 dot + LDS scale lookup + coalesced store
    #pragma unroll
    for (int m = 0; m < EPT; ++m) {
        int d = 0;
        d = dot4i8((int)kv0[m].x, (int)qv0[m].x, d);
        d = dot4i8((int)kv0[m].y, (int)qv0[m].y, d);
        d = dot4i8((int)kv0[m].z, (int)qv0[m].z, d);
        d = dot4i8((int)kv0[m].w, (int)qv0[m].w, d);
        d = dot4i8((int)kv1[m].x, (int)qv1[m].x, d);
        d = dot4i8((int)kv1[m].y, (int)qv1[m].y, d);
        d = dot4i8((int)kv1[m].z, (int)qv1[m].z, d);
        d = dot4i8((int)kv1[m].w, (int)qv1[m].w, d);
        const float skx = __half2float(ssk[xs[m]]);
        const float sqy = __half2float(ssq[ys[m]]);
        const int e = base_e + m * 512 + t;
        out[gbase + e] = (float)d * skx * sqy * 0.17677669529663687f;
    }
}

// ---------------------------------------------------------------------------
extern "C" void kernel_launch(void* const* d_in, const int* in_sizes, int n_in,
                              void* d_out, int out_size, void* d_ws, size_t ws_size,
                              hipStream_t stream) {
    // Input order: indices, img, features, Wk, bk, Wq, bq
    const int*   indices  = (const int*)d_in[0];
    const float* features = (const float*)d_in[2];
    const float* Wk       = (const float*)d_in[3];
    const float* bk       = (const float*)d_in[4];
    const float* Wq       = (const float*)d_in[5];
    const float* bq       = (const float*)d_in[6];
    float* out = (float*)d_out;

    // ws layout: ks8 (2MB) | qs8 (2MB) | sk (128KB f16) | sq (128KB f16)
    signed char* ks8 = (signed char*)d_ws;
    signed char* qs8 = ks8 + (size_t)TOTAL_NODES * 32;
    __half* sk = (__half*)(qs8 + (size_t)TOTAL_NODES * 32);
    __half* sq = sk + TOTAL_NODES;

    const int* xidx = indices + (size_t)1 * TOTAL_EDGES;  // row 1 -> keys
    const int* yidx = indices + (size_t)2 * TOTAL_EDGES;  // row 2 -> queries

    proj_kernel<<<TOTAL_NODES / 64, 256, 0, stream>>>(
        features, Wk, bk, Wq, bq, ks8, qs8, sk, sq);
    edge_kernel<<<BB * 512, 512, 0, stream>>>(xidx, yidx, ks8, qs8, sk, sq, out);
}

// Round 16
// 74.430 us; speedup vs baseline: 2.6070x; 1.0404x over previous
//
#include <hip/hip_runtime.h>
#include <hip/hip_fp16.h>

#define LATENT 128
#define DQK    32
#define BB     4
#define NN     16384
#define KK     64
#define TOTAL_EDGES (BB * NN * KK)   // 4,194,304
#define TOTAL_NODES (BB * NN)        // 65,536
#define PADF   132                   // f32 LDS row stride (floats)
#define EPT    4                     // edges per thread (edge kernel)

// ---------------------------------------------------------------------------
// i8 dot helper: 4 x i8 pairs -> i32 accumulate
// ---------------------------------------------------------------------------
__device__ __forceinline__ int dot4i8(int a, int b, int c) {
#if __has_builtin(__builtin_amdgcn_sdot4)
    return __builtin_amdgcn_sdot4(a, b, c, false);
#else
    c += ((a << 24) >> 24) * ((b << 24) >> 24);
    c += ((a << 16) >> 24) * ((b << 16) >> 24);
    c += ((a <<  8) >> 24) * ((b <<  8) >> 24);
    c += (a >> 24) * (b >> 24);
    return c;
#endif
}

// ---------------------------------------------------------------------------
// Kernel 1: proj + int8 row quantization (best-measured r8 version, ~13 us).
// LDS-tiled f32 GEMM, 4x4 micro-tile; epilogue: per-row absmax over the 16
// tx-lanes via shfl_xor, rint-quantize to i8, per-row f16 scale.
// ---------------------------------------------------------------------------
__global__ __launch_bounds__(256, 2) void proj_kernel(
    const float* __restrict__ features,  // [B*N, 128]
    const float* __restrict__ Wk,        // [32, 128]
    const float* __restrict__ bk,        // [32]
    const float* __restrict__ Wq,        // [32, 128]
    const float* __restrict__ bq,        // [32]
    signed char* __restrict__ ks8,       // [B*N, 32] i8
    signed char* __restrict__ qs8,       // [B*N, 32] i8
    __half* __restrict__ sk,             // [B*N] f16 row scales
    __half* __restrict__ sq)
{
    __shared__ float sf[64 * PADF];
    __shared__ float sw[64 * PADF];      // rows 0..31 = Wk, 32..63 = Wq
    __shared__ float sb[64];

    const int t = threadIdx.x;
    const int node0 = blockIdx.x * 64;

    #pragma unroll
    for (int j = 0; j < 8; ++j) {
        int idx = t + j * 256;
        int r = idx >> 5;
        int c = idx & 31;
        const float4* src = (r < 32) ? (const float4*)Wk : (const float4*)Wq;
        float4 v = src[(size_t)(r & 31) * 32 + c];
        *(float4*)&sw[r * PADF + c * 4] = v;
    }
    if (t < 64) sb[t] = (t < 32) ? bk[t] : bq[t - 32];

    #pragma unroll
    for (int j = 0; j < 8; ++j) {
        int idx = t + j * 256;
        int r = idx >> 5;
        int c = idx & 31;
        float4 v = ((const float4*)(features + (size_t)(node0 + r) * LATENT))[c];
        *(float4*)&sf[r * PADF + c * 4] = v;
    }
    __syncthreads();

    const int tx = t & 15;               // dims tx + 16u
    const int ty = t >> 4;               // nodes ty*4 + i

    float acc[4][4];
    #pragma unroll
    for (int i = 0; i < 4; ++i)
        #pragma unroll
        for (int u = 0; u < 4; ++u) acc[i][u] = 0.f;

    #pragma unroll 4
    for (int kk = 0; kk < 32; ++kk) {
        float4 a[4], b[4];
        #pragma unroll
        for (int i = 0; i < 4; ++i)
            a[i] = *(const float4*)&sf[(ty * 4 + i) * PADF + kk * 4];
        #pragma unroll
        for (int u = 0; u < 4; ++u)
            b[u] = *(const float4*)&sw[(tx + 16 * u) * PADF + kk * 4];
        #pragma unroll
        for (int i = 0; i < 4; ++i)
            #pragma unroll
            for (int u = 0; u < 4; ++u)
                acc[i][u] += a[i].x * b[u].x + a[i].y * b[u].y
                           + a[i].z * b[u].z + a[i].w * b[u].w;
    }

    // ---- quantizing epilogue ----
    float vk0[4], vk1[4], vq0[4], vq1[4], mk[4], mq[4];
    #pragma unroll
    for (int i = 0; i < 4; ++i) {
        vk0[i] = acc[i][0] + sb[tx];
        vk1[i] = acc[i][1] + sb[tx + 16];
        vq0[i] = acc[i][2] + sb[tx + 32];
        vq1[i] = acc[i][3] + sb[tx + 48];
        mk[i] = fmaxf(fabsf(vk0[i]), fabsf(vk1[i]));
        mq[i] = fmaxf(fabsf(vq0[i]), fabsf(vq1[i]));
    }
    #pragma unroll
    for (int mask = 1; mask < 16; mask <<= 1) {
        #pragma unroll
        for (int i = 0; i < 4; ++i) {
            mk[i] = fmaxf(mk[i], __shfl_xor(mk[i], mask));
            mq[i] = fmaxf(mq[i], __shfl_xor(mq[i], mask));
        }
    }
    #pragma unroll
    for (int i = 0; i < 4; ++i) {
        const int node = node0 + ty * 4 + i;
        const float invk = (mk[i] > 0.f) ? 127.f / mk[i] : 0.f;
        const float invq = (mq[i] > 0.f) ? 127.f / mq[i] : 0.f;
        signed char* kr = ks8 + (size_t)node * 32;
        signed char* qr = qs8 + (size_t)node * 32;
        kr[tx]      = (signed char)__float2int_rn(vk0[i] * invk);
        kr[tx + 16] = (signed char)__float2int_rn(vk1[i] * invk);
        qr[tx]      = (signed char)__float2int_rn(vq0[i] * invq);
        qr[tx + 16] = (signed char)__float2int_rn(vq1[i] * invq);
        if (tx == 0) {
            sk[node] = __float2half(mk[i] * (1.f / 127.f));
            sq[node] = __float2half(mq[i] * (1.f / 127.f));
        }
    }
}

// ---------------------------------------------------------------------------
// Kernel 2: i8 edge dots (best-measured r8 config, ~50 us).
// 1 lane = 1 edge, EPT=4 pipelined; 4 divergent 16B lane-requests / 2 random
// 64B line-touches per edge — measured hardware floor (invariant to occupancy,
// MLP, L1/L2 cache policy, and VALU work across r6/r8/r9/r11/r14/r15).
// Scales staged in LDS (64KB) -> DS pipe; indices/outputs coalesced.
// ---------------------------------------------------------------------------
__global__ __launch_bounds__(512, 2) void edge_kernel(
    const int* __restrict__ xidx,        // indices row 1, [B*N*K]
    const int* __restrict__ yidx,        // indices row 2
    const signed char* __restrict__ ks8, // [B*N, 32] i8
    const signed char* __restrict__ qs8,
    const __half* __restrict__ sk,       // [B*N] f16
    const __half* __restrict__ sq,
    float* __restrict__ out)             // [B*N*K]
{
    __shared__ __half ssk[NN];           // 32 KB
    __shared__ __half ssq[NN];           // 32 KB

    const int t = threadIdx.x;
    const int b = blockIdx.x >> 9;       // 512 blocks per batch

    // Stage scale tables (coalesced uint4: 2048 per table, 4/thread each)
    const uint4* gk = (const uint4*)(sk + (size_t)b * NN);
    const uint4* gq = (const uint4*)(sq + (size_t)b * NN);
    uint4* lk = (uint4*)ssk;
    uint4* lq = (uint4*)ssq;
    #pragma unroll
    for (int j = 0; j < 4; ++j) {
        lk[t + j * 512] = gk[t + j * 512];
        lq[t + j * 512] = gq[t + j * 512];
    }
    __syncthreads();

    const int base_e = (blockIdx.x & 511) * (512 * EPT);  // within batch
    const int gbase  = b << 20;                            // batch edge offset
    const size_t nodebase = (size_t)b << 14;               // b * NN

    // Phase 1: coalesced index loads
    int xs[EPT], ys[EPT];
    #pragma unroll
    for (int m = 0; m < EPT; ++m) {
        const int e = base_e + m * 512 + t;
        xs[m] = xidx[gbase + e];
        ys[m] = yidx[gbase + e];
    }
    __builtin_amdgcn_sched_barrier(0);

    // Phase 2: all divergent gathers in flight (4 per edge, 16 total)
    uint4 kv0[EPT], kv1[EPT], qv0[EPT], qv1[EPT];
    const uint4* k4 = (const uint4*)ks8;
    const uint4* q4 = (const uint4*)qs8;
    #pragma unroll
    for (int m = 0; m < EPT; ++m) {
        const size_t xo = (nodebase + (size_t)xs[m]) << 1;  // uint4 units
        const size_t yo = (nodebase + (size_t)ys[m]) << 1;
        kv0[m] = k4[xo];
        kv1[m] = k4[xo + 1];
        qv0[m] = q4[yo];
        qv1[m] = q4[yo + 1];
    }
    __builtin_amdgcn_sched_barrier(0);

    // Phase 3: lane-local i8 dot + LDS scale lookup + coalesced store
    #pragma unroll
    for (int m = 0; m < EPT; ++m) {
        int d = 0;
        d = dot4i8((int)kv0[m].x, (int)qv0[m].x, d);
        d = dot4i8((int)kv0[m].y, (int)qv0[m].y, d);
        d = dot4i8((int)kv0[m].z, (int)qv0[m].z, d);
        d = dot4i8((int)kv0[m].w, (int)qv0[m].w, d);
        d = dot4i8((int)kv1[m].x, (int)qv1[m].x, d);
        d = dot4i8((int)kv1[m].y, (int)qv1[m].y, d);
        d = dot4i8((int)kv1[m].z, (int)qv1[m].z, d);
        d = dot4i8((int)kv1[m].w, (int)qv1[m].w, d);
        const float skx = __half2float(ssk[xs[m]]);
        const float sqy = __half2float(ssq[ys[m]]);
        const int e = base_e + m * 512 + t;
        out[gbase + e] = (float)d * skx * sqy * 0.17677669529663687f;
    }
}

// ---------------------------------------------------------------------------
extern "C" void kernel_launch(void* const* d_in, const int* in_sizes, int n_in,
                              void* d_out, int out_size, void* d_ws, size_t ws_size,
                              hipStream_t stream) {
    // Input order: indices, img, features, Wk, bk, Wq, bq
    const int*   indices  = (const int*)d_in[0];
    const float* features = (const float*)d_in[2];
    const float* Wk       = (const float*)d_in[3];
    const float* bk       = (const float*)d_in[4];
    const float* Wq       = (const float*)d_in[5];
    const float* bq       = (const float*)d_in[6];
    float* out = (float*)d_out;

    // ws layout: ks8 (2MB) | qs8 (2MB) | sk (128KB f16) | sq (128KB f16)
    signed char* ks8 = (signed char*)d_ws;
    signed char* qs8 = ks8 + (size_t)TOTAL_NODES * 32;
    __half* sk = (__half*)(qs8 + (size_t)TOTAL_NODES * 32);
    __half* sq = sk + TOTAL_NODES;

    const int* xidx = indices + (size_t)1 * TOTAL_EDGES;  // row 1 -> keys
    const int* yidx = indices + (size_t)2 * TOTAL_EDGES;  // row 2 -> queries

    proj_kernel<<<TOTAL_NODES / 64, 256, 0, stream>>>(
        features, Wk, bk, Wq, bq, ks8, qs8, sk, sq);
    // 512 blocks/batch x 4 batches; 512 threads x EPT(4) edges = 2048 edges/block
    edge_kernel<<<BB * 512, 512, 0, stream>>>(xidx, yidx, ks8, qs8, sk, sq, out);
}